// Round 5
// baseline (217.368 us; speedup 1.0000x reference)
//
#include <hip/hip_runtime.h>
#include <hip/hip_bf16.h>
#include <cstdint>

typedef __attribute__((ext_vector_type(8))) short short8;
typedef __attribute__((ext_vector_type(4))) float f32x4;

static constexpr int HWPIX = 16384;   // 128*128
static constexpr int NCH   = 512;
static constexpr int GCHK  = 32;      // gram pixel chunks (512 px each)

__device__ __forceinline__ unsigned short f2bf(float f) {
    unsigned int u = __float_as_uint(f);
    u = (u + 0x7fffu + ((u >> 16) & 1u)) >> 16;
    return (unsigned short)u;
}

// Conv tile: 64co x 256px (2 rows x 128 cols). K-dim order: kw outer,
// icr = ic*RT + absrow inner (RT = K+1 staged rows), padded to SROW.
// SROW forced to  == 8 mod 16 (16B units odd) -> 2-way-max bank aliasing on
// strided b128 reads (free per m136).
template<int K> struct KG {
    static constexpr int RT    = K + 1;
    static constexpr int SROW0 = ((3 * RT + 7) / 8) * 8;
    static constexpr int SROW  = (SROW0 % 16 == 0) ? SROW0 + 8 : SROW0;
    static constexpr int SPC   = SROW / 8;           // segments per kw column
    static constexpr int SEGS  = K * SPC;
    static constexpr int NCHK  = (SEGS + 3) / 4;     // MFMA K-32 chunks
    static constexpr int COLS  = 128 + K - 1;
    static constexpr int XSE   = COLS * SROW;
};
static_assert(KG<55>::XSE == 30576, "lds size");

struct PtrArgs {
    const float* w[8];
    const float* bias[8];
    unsigned short* wpk[8];
    int cum[9];            // cumulative NCHK per filter
};

// ---------------- weight repack: per (chunk, dr) ----------------
// layout per filter: [dr][t][lg 0..3][co 0..63] x 8 elems
template<int K>
__device__ void repack_body(const float* __restrict__ w, unsigned short* __restrict__ wpk,
                            int t, int dr)
{
    constexpr int RT   = KG<K>::RT;
    constexpr int SPC  = KG<K>::SPC;
    constexpr int SEGS = KG<K>::SEGS;
    constexpr int NCHK = KG<K>::NCHK;
    const int tid = threadIdx.x;        // lg*64 + co
    const int seg = t * 4 + (tid >> 6);
    const int co  = tid & 63;
    int kw = 0, r = 0;
    const bool vseg = seg < SEGS;
    if (vseg) { kw = seg / SPC; r = seg - kw * SPC; }
    short8 o;
    #pragma unroll
    for (int j = 0; j < 8; ++j) {
        const int icr = r * 8 + j;
        const int ic  = icr / RT;
        const int ar  = icr - ic * RT;
        const int kh  = ar - dr;
        float v = 0.f;
        if (vseg && icr < 3 * RT && kh >= 0 && kh < K)
            v = w[((co * 3 + ic) * K + kh) * K + kw];
        o[j] = (short)f2bf(v);
    }
    *reinterpret_cast<short8*>(wpk + (size_t)dr * NCHK * 2048 + (size_t)(t * 256 + tid) * 8) = o;
}

__global__ __launch_bounds__(256) void repack_all(PtrArgs a) {
    const int blk = blockIdx.x;
    const int dr  = blockIdx.y;
    int f = 0;
    #pragma unroll
    for (int i = 0; i < 8; ++i) if (blk >= a.cum[i + 1]) f = i + 1;
    const int t = blk - a.cum[f];
    switch (f) {
        case 0: repack_body< 3>(a.w[0], a.wpk[0], t, dr); break;
        case 1: repack_body< 5>(a.w[1], a.wpk[1], t, dr); break;
        case 2: repack_body< 7>(a.w[2], a.wpk[2], t, dr); break;
        case 3: repack_body<11>(a.w[3], a.wpk[3], t, dr); break;
        case 4: repack_body<15>(a.w[4], a.wpk[4], t, dr); break;
        case 5: repack_body<23>(a.w[5], a.wpk[5], t, dr); break;
        case 6: repack_body<37>(a.w[6], a.wpk[6], t, dr); break;
        case 7: repack_body<55>(a.w[7], a.wpk[7], t, dr); break;
    }
}

// ---------------- conv: 512 thr, 8 waves, 64co x 256px ----------------
template<int K>
__device__ void conv_body(const float* __restrict__ x, const unsigned short* __restrict__ wpk,
                          const float* __restrict__ bias, unsigned short* __restrict__ feat,
                          int cbase, unsigned short* xs, int bx)
{
    constexpr int P    = (K - 1) / 2;
    constexpr int RT   = KG<K>::RT;
    constexpr int SROW = KG<K>::SROW;
    constexpr int SPC  = KG<K>::SPC;
    constexpr int SEGS = KG<K>::SEGS;
    constexpr int NCHK = KG<K>::NCHK;
    constexpr int COLS = KG<K>::COLS;

    const int tid = threadIdx.x;
    const int b   = bx >> 6;            // batch
    const int h0  = (bx & 63) * 2;      // first of 2 output rows

    // stage receptive field: xs[c][icr] = x[ic][h0+absrow-P][c-P]
    const float* xb = x + (size_t)b * 3 * HWPIX;
    for (int idx = tid; idx < SROW * COLS; idx += 512) {
        const int icr = idx / COLS;
        const int c   = idx - icr * COLS;
        float v = 0.f;
        if (icr < 3 * RT) {
            const int ic  = icr / RT;
            const int ar  = icr - ic * RT;
            const int row = h0 + ar - P;
            const int col = c - P;
            if ((unsigned)row < 128u && (unsigned)col < 128u)
                v = xb[ic * HWPIX + row * 128 + col];
        }
        xs[c * SROW + icr] = f2bf(v);
    }
    __syncthreads();

    const int lane = tid & 63;
    const int wv   = tid >> 6;          // 0..7
    const int dr   = wv >> 2;           // output row offset 0..1
    const int colq = (wv & 3) * 32;     // 32-px column group
    const int ln15 = lane & 15;
    const int lg   = lane >> 4;         // k-octet 0..3

    f32x4 acc[4][2] = {};
    const unsigned short* wpkd = wpk + (size_t)dr * NCHK * 2048;

    for (int t = 0; t < NCHK; ++t) {
        const int seg = t * 4 + lg;
        int kw = 0, r = 0;
        if (seg < SEGS) { kw = seg / SPC; r = seg - kw * SPC; }   // tail: zero wgts
        const unsigned short* ap = wpkd + (size_t)t * 2048 + lg * 512 + ln15 * 8;
        short8 a0 = *reinterpret_cast<const short8*>(ap);
        short8 a1 = *reinterpret_cast<const short8*>(ap + 128);
        short8 a2 = *reinterpret_cast<const short8*>(ap + 256);
        short8 a3 = *reinterpret_cast<const short8*>(ap + 384);
        const unsigned short* bp = xs + (colq + ln15 + kw) * SROW + r * 8;
        short8 b0 = *reinterpret_cast<const short8*>(bp);
        short8 b1 = *reinterpret_cast<const short8*>(bp + 16 * SROW);
        acc[0][0] = __builtin_amdgcn_mfma_f32_16x16x32_bf16(a0, b0, acc[0][0], 0, 0, 0);
        acc[0][1] = __builtin_amdgcn_mfma_f32_16x16x32_bf16(a0, b1, acc[0][1], 0, 0, 0);
        acc[1][0] = __builtin_amdgcn_mfma_f32_16x16x32_bf16(a1, b0, acc[1][0], 0, 0, 0);
        acc[1][1] = __builtin_amdgcn_mfma_f32_16x16x32_bf16(a1, b1, acc[1][1], 0, 0, 0);
        acc[2][0] = __builtin_amdgcn_mfma_f32_16x16x32_bf16(a2, b0, acc[2][0], 0, 0, 0);
        acc[2][1] = __builtin_amdgcn_mfma_f32_16x16x32_bf16(a2, b1, acc[2][1], 0, 0, 0);
        acc[3][0] = __builtin_amdgcn_mfma_f32_16x16x32_bf16(a3, b0, acc[3][0], 0, 0, 0);
        acc[3][1] = __builtin_amdgcn_mfma_f32_16x16x32_bf16(a3, b1, acc[3][1], 0, 0, 0);
    }

    const int orow = h0 + dr;
    #pragma unroll
    for (int s = 0; s < 4; ++s)
        #pragma unroll
        for (int nf = 0; nf < 2; ++nf)
            #pragma unroll
            for (int i = 0; i < 4; ++i) {
                const int co = s * 16 + lg * 4 + i;
                const int pc = colq + nf * 16 + ln15;
                float vv = fmaxf(acc[s][nf][i] + bias[co], 0.f);
                feat[((size_t)(b * NCH + cbase + co)) * HWPIX + orow * 128 + pc] = f2bf(vv);
            }
}

__global__ __launch_bounds__(512) void conv_all(const float* __restrict__ x,
                                                PtrArgs a, unsigned short* __restrict__ feat)
{
    __shared__ __align__(16) unsigned short xs[KG<55>::XSE];
    switch (blockIdx.y) {
        case 0: conv_body< 3>(x, a.wpk[0], a.bias[0], feat, 0 * 64, xs, blockIdx.x); break;
        case 1: conv_body< 5>(x, a.wpk[1], a.bias[1], feat, 1 * 64, xs, blockIdx.x); break;
        case 2: conv_body< 7>(x, a.wpk[2], a.bias[2], feat, 2 * 64, xs, blockIdx.x); break;
        case 3: conv_body<11>(x, a.wpk[3], a.bias[3], feat, 3 * 64, xs, blockIdx.x); break;
        case 4: conv_body<15>(x, a.wpk[4], a.bias[4], feat, 4 * 64, xs, blockIdx.x); break;
        case 5: conv_body<23>(x, a.wpk[5], a.bias[5], feat, 5 * 64, xs, blockIdx.x); break;
        case 6: conv_body<37>(x, a.wpk[6], a.bias[6], feat, 6 * 64, xs, blockIdx.x); break;
        case 7: conv_body<55>(x, a.wpk[7], a.bias[7], feat, 7 * 64, xs, blockIdx.x); break;
    }
}

// ---------------- gram via MFMA (unchanged from passing round) ----------------
__global__ __launch_bounds__(256) void gram_mfma(
    const unsigned short* __restrict__ feat, const int* __restrict__ perm,
    float* __restrict__ part)
{
    __shared__ __align__(16) unsigned short tile[64 * 256];
    __shared__ int permch[64];

    const int bg = blockIdx.y, chunk = blockIdx.x;
    const int b = bg >> 3, gq = bg & 7;
    const int tid = threadIdx.x;

    if (tid < 64) permch[tid] = perm[gq * 64 + tid];
    __syncthreads();

    const int lane = tid & 63;
    const int wv   = tid >> 6;
    const int ln15 = lane & 15;
    const int kg   = lane >> 4;

    f32x4 acc[4] = {};
    const size_t pxbase = (size_t)chunk * 512;

    for (int p2 = 0; p2 < 2; ++p2) {
        {
            const int r0 = tid >> 5;        // 0..7
            const int g  = tid & 31;        // 16B group 0..31
            #pragma unroll
            for (int it = 0; it < 8; ++it) {
                const int r = it * 8 + r0;
                const unsigned short* src =
                    feat + (((size_t)(b * NCH + permch[r])) << 14) + pxbase + p2 * 256 + g * 8;
                short8 v = *reinterpret_cast<const short8*>(src);
                *reinterpret_cast<short8*>(tile + r * 256 + ((g ^ (r & 7)) * 8)) = v;
            }
        }
        __syncthreads();
        #pragma unroll
        for (int t = 0; t < 8; ++t) {
            const int g  = t * 4 + kg;
            const int ra = wv * 16 + ln15;
            short8 av = *reinterpret_cast<const short8*>(tile + ra * 256 + ((g ^ (ra & 7)) * 8));
            #pragma unroll
            for (int cs = 0; cs < 4; ++cs) {
                const int rb = cs * 16 + ln15;
                short8 bv = *reinterpret_cast<const short8*>(tile + rb * 256 + ((g ^ (rb & 7)) * 8));
                acc[cs] = __builtin_amdgcn_mfma_f32_16x16x32_bf16(av, bv, acc[cs], 0, 0, 0);
            }
        }
        __syncthreads();
    }

    float* pp = part + ((size_t)bg * GCHK + chunk) * 4096;
    #pragma unroll
    for (int cs = 0; cs < 4; ++cs)
        #pragma unroll
        for (int i = 0; i < 4; ++i) {
            const int row = wv * 16 + kg * 4 + i;
            const int col = cs * 16 + ln15;
            pp[row * 64 + col] = acc[cs][i];
        }
}

__global__ __launch_bounds__(256) void gram_reduce(
    const float* __restrict__ part, float* __restrict__ out)
{
    const int idx = blockIdx.x * 256 + threadIdx.x;   // 0..65535
    const int bg  = idx >> 12;
    const int e   = idx & 4095;
    const float* p = part + (size_t)bg * GCHK * 4096 + e;
    float s = 0.f;
    #pragma unroll
    for (int c = 0; c < GCHK; ++c) s += p[c * 4096];
    out[idx] = s;
}

extern "C" void kernel_launch(void* const* d_in, const int* in_sizes, int n_in,
                              void* d_out, int out_size, void* d_ws, size_t ws_size,
                              hipStream_t stream) {
    const float* x = (const float*)d_in[0];
    const int* perm = (const int*)d_in[17];

    // ws: feat bf16 32MiB | part 8MiB | wpk ~4.4MiB
    unsigned short* feat = (unsigned short*)d_ws;
    float* part = (float*)((char*)d_ws + (size_t)2 * NCH * HWPIX * sizeof(unsigned short));
    unsigned short* wpk0 = (unsigned short*)((char*)part + (size_t)16 * GCHK * 4096 * sizeof(float));
    float* out = (float*)d_out;

    const int nchk[8] = { KG<3>::NCHK, KG<5>::NCHK, KG<7>::NCHK, KG<11>::NCHK,
                          KG<15>::NCHK, KG<23>::NCHK, KG<37>::NCHK, KG<55>::NCHK };
    PtrArgs a;
    int acc = 0;
    for (int i = 0; i < 8; ++i) {
        a.w[i]    = (const float*)d_in[1 + 2 * i];
        a.bias[i] = (const float*)d_in[2 + 2 * i];
        a.wpk[i]  = wpk0 + (size_t)acc * 2 * 2048;   // 2 dr variants per chunk
        a.cum[i]  = acc;
        acc += nchk[i];
    }
    a.cum[8] = acc;   // 534 total chunks

    repack_all<<<dim3(acc, 2), 256, 0, stream>>>(a);
    conv_all<<<dim3(128, 8), 512, 0, stream>>>(x, a, feat);
    gram_mfma<<<dim3(GCHK, 16), 256, 0, stream>>>(feat, perm, part);
    gram_reduce<<<dim3(65536 / 256), 256, 0, stream>>>(part, out);
}

// Round 6
// 170.988 us; speedup vs baseline: 1.2712x; 1.2712x over previous
//
#include <hip/hip_runtime.h>
#include <hip/hip_bf16.h>
#include <cstdint>

typedef __attribute__((ext_vector_type(8))) short short8;
typedef __attribute__((ext_vector_type(4))) short short4v;
typedef __attribute__((ext_vector_type(4))) float f32x4;

static constexpr int HWPIX = 16384;   // 128*128
static constexpr int NCH   = 512;
static constexpr int GCHK  = 32;      // gram pixel chunks (512 px each)

__device__ __forceinline__ unsigned short f2bf(float f) {
    unsigned int u = __float_as_uint(f);
    u = (u + 0x7fffu + ((u >> 16) & 1u)) >> 16;
    return (unsigned short)u;
}

// Conv tile: 64co x 128px (one image row). K-dim: kw outer, icr=ic*K+kh inner,
// padded to SROW = SPC*8 with SPC forced ODD -> B-frag reads at stride SPC*16B
// are 2-way bank aliasing max (free per m136), and 16B-aligned.
template<int K> struct KG {
    static constexpr int P    = (K - 1) / 2;
    static constexpr int SPC0 = (3 * K + 7) / 8;
    static constexpr int SPC  = (SPC0 & 1) ? SPC0 : SPC0 + 1;
    static constexpr int SROW = SPC * 8;
    static constexpr int SEGS = K * SPC;
    static constexpr int NCHK = (SEGS + 3) / 4;      // MFMA K-32 chunks
    static constexpr int COLS = 128 + K - 1;
    static constexpr int XSE  = COLS * SROW;
};
static_assert(KG<55>::XSE == 30576, "lds size");
static_assert(KG<55>::XSE * 2 <= 65536, "static LDS limit");

struct PtrArgs {
    const float* w[8];
    const float* bias[8];
    unsigned short* wpk[8];
    int cum[9];            // cumulative NCHK per filter
};

// ---------------- weight repack ----------------
// layout per filter: [t][tid][8] ; tid -> co=(tid>>6)*16+(tid&15), seg=t*4+((tid>>4)&3)
template<int K>
__device__ void repack_body(const float* __restrict__ w, unsigned short* __restrict__ wpk, int t) {
    constexpr int SPC  = KG<K>::SPC;
    constexpr int SEGS = KG<K>::SEGS;
    const int tid = threadIdx.x;
    const int co  = ((tid >> 6) << 4) + (tid & 15);
    const int seg = t * 4 + ((tid >> 4) & 3);
    int kw = 0, r = 0;
    const bool vseg = seg < SEGS;
    if (vseg) { kw = seg / SPC; r = seg - kw * SPC; }
    short8 o;
    #pragma unroll
    for (int j = 0; j < 8; ++j) {
        const int icr = r * 8 + j;
        float v = 0.f;
        if (vseg && icr < 3 * K) {
            const int ic = icr / K;
            const int kh = icr - ic * K;
            v = w[((co * 3 + ic) * K + kh) * K + kw];
        }
        o[j] = (short)f2bf(v);
    }
    *reinterpret_cast<short8*>(wpk + ((size_t)(t * 256 + tid)) * 8) = o;
}

__global__ __launch_bounds__(256) void repack_all(PtrArgs a) {
    const int blk = blockIdx.x;
    int f = 0;
    #pragma unroll
    for (int i = 0; i < 8; ++i) if (blk >= a.cum[i + 1]) f = i + 1;
    const int t = blk - a.cum[f];
    switch (f) {
        case 0: repack_body< 3>(a.w[0], a.wpk[0], t); break;
        case 1: repack_body< 5>(a.w[1], a.wpk[1], t); break;
        case 2: repack_body< 7>(a.w[2], a.wpk[2], t); break;
        case 3: repack_body<11>(a.w[3], a.wpk[3], t); break;
        case 4: repack_body<15>(a.w[4], a.wpk[4], t); break;
        case 5: repack_body<23>(a.w[5], a.wpk[5], t); break;
        case 6: repack_body<37>(a.w[6], a.wpk[6], t); break;
        case 7: repack_body<55>(a.w[7], a.wpk[7], t); break;
    }
}

// ---------------- conv: 256 thr, 4 waves; wave = 64co x 32px ----------------
#define MFMA_BF16 __builtin_amdgcn_mfma_f32_16x16x32_bf16

template<int K>
__device__ void conv_body(const float* __restrict__ x, const unsigned short* __restrict__ wpk,
                          const float* __restrict__ bias, unsigned short* __restrict__ feat,
                          int cbase, unsigned short* xs, int bx)
{
    constexpr int P    = KG<K>::P;
    constexpr int SPC  = KG<K>::SPC;
    constexpr int SROW = KG<K>::SROW;
    constexpr int SEGS = KG<K>::SEGS;
    constexpr int NCHK = KG<K>::NCHK;
    constexpr int COLS = KG<K>::COLS;

    const int tid = threadIdx.x;
    const int b   = bx >> 7;            // batch
    const int h   = bx & 127;           // image row

    // stage receptive field: xs[c][icr]; 4 icr per thread, one ds_write_b64
    const float* xb = x + (size_t)b * 3 * HWPIX;
    for (int e = tid * 4; e < SROW * COLS; e += 256 * 4) {
        const int c  = e / SROW;
        const int i0 = e - c * SROW;
        short4v pk;
        #pragma unroll
        for (int j = 0; j < 4; ++j) {
            const int icr = i0 + j;
            float v = 0.f;
            if (icr < 3 * K) {
                const int ic  = icr / K;
                const int kh  = icr - ic * K;
                const int row = h + kh - P;
                const int col = c - P;
                if ((unsigned)row < 128u && (unsigned)col < 128u)
                    v = xb[ic * HWPIX + row * 128 + col];
            }
            pk[j] = (short)f2bf(v);
        }
        *reinterpret_cast<short4v*>(xs + e) = pk;
    }
    __syncthreads();

    const int lane = tid & 63;
    const int wv   = tid >> 6;          // 0..3 -> 32-px strip
    const int ln15 = lane & 15;
    const int lg   = lane >> 4;         // k-octet 0..3
    const int wvpx = wv * 32;

    f32x4 acc[4][2] = {};
    const unsigned short* wl = wpk + (size_t)lane * 8;

    // A chunk 0 in regs; prefetch next each iter (clamped, in-bounds)
    short8 a0 = *reinterpret_cast<const short8*>(wl + 0);
    short8 a1 = *reinterpret_cast<const short8*>(wl + 512);
    short8 a2 = *reinterpret_cast<const short8*>(wl + 1024);
    short8 a3 = *reinterpret_cast<const short8*>(wl + 1536);

    for (int t = 0; t < NCHK; ++t) {
        const int tn = (t + 1 < NCHK) ? t + 1 : t;
        const unsigned short* wn = wl + (size_t)tn * 2048;
        short8 n0 = *reinterpret_cast<const short8*>(wn + 0);
        short8 n1 = *reinterpret_cast<const short8*>(wn + 512);
        short8 n2 = *reinterpret_cast<const short8*>(wn + 1024);
        short8 n3 = *reinterpret_cast<const short8*>(wn + 1536);

        const int seg = t * 4 + lg;
        int kw = 0, r = 0;
        if (seg < SEGS) { kw = seg / SPC; r = seg - kw * SPC; }   // tail: zero wgts
        const unsigned short* bp = xs + (wvpx + ln15 + kw) * SROW + r * 8;
        short8 b0 = *reinterpret_cast<const short8*>(bp);
        short8 b1 = *reinterpret_cast<const short8*>(bp + 16 * SROW);

        acc[0][0] = MFMA_BF16(a0, b0, acc[0][0], 0, 0, 0);
        acc[0][1] = MFMA_BF16(a0, b1, acc[0][1], 0, 0, 0);
        acc[1][0] = MFMA_BF16(a1, b0, acc[1][0], 0, 0, 0);
        acc[1][1] = MFMA_BF16(a1, b1, acc[1][1], 0, 0, 0);
        acc[2][0] = MFMA_BF16(a2, b0, acc[2][0], 0, 0, 0);
        acc[2][1] = MFMA_BF16(a2, b1, acc[2][1], 0, 0, 0);
        acc[3][0] = MFMA_BF16(a3, b0, acc[3][0], 0, 0, 0);
        acc[3][1] = MFMA_BF16(a3, b1, acc[3][1], 0, 0, 0);

        a0 = n0; a1 = n1; a2 = n2; a3 = n3;
    }

    const int orow = h * 128;
    #pragma unroll
    for (int s = 0; s < 4; ++s)
        #pragma unroll
        for (int q = 0; q < 2; ++q)
            #pragma unroll
            for (int i = 0; i < 4; ++i) {
                const int co = s * 16 + lg * 4 + i;
                const int px = wvpx + q * 16 + ln15;
                float vv = fmaxf(acc[s][q][i] + bias[co], 0.f);
                feat[((size_t)(b * NCH + cbase + co)) * HWPIX + orow + px] = f2bf(vv);
            }
}

__global__ __launch_bounds__(256) void conv_all(const float* __restrict__ x,
                                                PtrArgs a, unsigned short* __restrict__ feat)
{
    __shared__ __align__(16) unsigned short xs[KG<55>::XSE];
    // LPT dispatch: heaviest filter (K=55) first so it spreads over all CUs
    switch (7 - blockIdx.y) {
        case 0: conv_body< 3>(x, a.wpk[0], a.bias[0], feat, 0 * 64, xs, blockIdx.x); break;
        case 1: conv_body< 5>(x, a.wpk[1], a.bias[1], feat, 1 * 64, xs, blockIdx.x); break;
        case 2: conv_body< 7>(x, a.wpk[2], a.bias[2], feat, 2 * 64, xs, blockIdx.x); break;
        case 3: conv_body<11>(x, a.wpk[3], a.bias[3], feat, 3 * 64, xs, blockIdx.x); break;
        case 4: conv_body<15>(x, a.wpk[4], a.bias[4], feat, 4 * 64, xs, blockIdx.x); break;
        case 5: conv_body<23>(x, a.wpk[5], a.bias[5], feat, 5 * 64, xs, blockIdx.x); break;
        case 6: conv_body<37>(x, a.wpk[6], a.bias[6], feat, 6 * 64, xs, blockIdx.x); break;
        case 7: conv_body<55>(x, a.wpk[7], a.bias[7], feat, 7 * 64, xs, blockIdx.x); break;
    }
}

// ---------------- gram via MFMA (unchanged from passing round) ----------------
__global__ __launch_bounds__(256) void gram_mfma(
    const unsigned short* __restrict__ feat, const int* __restrict__ perm,
    float* __restrict__ part)
{
    __shared__ __align__(16) unsigned short tile[64 * 256];
    __shared__ int permch[64];

    const int bg = blockIdx.y, chunk = blockIdx.x;
    const int b = bg >> 3, gq = bg & 7;
    const int tid = threadIdx.x;

    if (tid < 64) permch[tid] = perm[gq * 64 + tid];
    __syncthreads();

    const int lane = tid & 63;
    const int wv   = tid >> 6;
    const int ln15 = lane & 15;
    const int kg   = lane >> 4;

    f32x4 acc[4] = {};
    const size_t pxbase = (size_t)chunk * 512;

    for (int p2 = 0; p2 < 2; ++p2) {
        {
            const int r0 = tid >> 5;        // 0..7
            const int g  = tid & 31;        // 16B group 0..31
            #pragma unroll
            for (int it = 0; it < 8; ++it) {
                const int r = it * 8 + r0;
                const unsigned short* src =
                    feat + (((size_t)(b * NCH + permch[r])) << 14) + pxbase + p2 * 256 + g * 8;
                short8 v = *reinterpret_cast<const short8*>(src);
                *reinterpret_cast<short8*>(tile + r * 256 + ((g ^ (r & 7)) * 8)) = v;
            }
        }
        __syncthreads();
        #pragma unroll
        for (int t = 0; t < 8; ++t) {
            const int g  = t * 4 + kg;
            const int ra = wv * 16 + ln15;
            short8 av = *reinterpret_cast<const short8*>(tile + ra * 256 + ((g ^ (ra & 7)) * 8));
            #pragma unroll
            for (int cs = 0; cs < 4; ++cs) {
                const int rb = cs * 16 + ln15;
                short8 bv = *reinterpret_cast<const short8*>(tile + rb * 256 + ((g ^ (rb & 7)) * 8));
                acc[cs] = MFMA_BF16(av, bv, acc[cs], 0, 0, 0);
            }
        }
        __syncthreads();
    }

    float* pp = part + ((size_t)bg * GCHK + chunk) * 4096;
    #pragma unroll
    for (int cs = 0; cs < 4; ++cs)
        #pragma unroll
        for (int i = 0; i < 4; ++i) {
            const int row = wv * 16 + kg * 4 + i;
            const int col = cs * 16 + ln15;
            pp[row * 64 + col] = acc[cs][i];
        }
}

__global__ __launch_bounds__(256) void gram_reduce(
    const float* __restrict__ part, float* __restrict__ out)
{
    const int idx = blockIdx.x * 256 + threadIdx.x;   // 0..65535
    const int bg  = idx >> 12;
    const int e   = idx & 4095;
    const float* p = part + (size_t)bg * GCHK * 4096 + e;
    float s = 0.f;
    #pragma unroll
    for (int c = 0; c < GCHK; ++c) s += p[c * 4096];
    out[idx] = s;
}

extern "C" void kernel_launch(void* const* d_in, const int* in_sizes, int n_in,
                              void* d_out, int out_size, void* d_ws, size_t ws_size,
                              hipStream_t stream) {
    const float* x = (const float*)d_in[0];
    const int* perm = (const int*)d_in[17];

    // ws: feat bf16 32MiB | part 8MiB | wpk ~2.1MiB
    unsigned short* feat = (unsigned short*)d_ws;
    float* part = (float*)((char*)d_ws + (size_t)2 * NCH * HWPIX * sizeof(unsigned short));
    unsigned short* wpk0 = (unsigned short*)((char*)part + (size_t)16 * GCHK * 4096 * sizeof(float));
    float* out = (float*)d_out;

    const int nchk[8] = { KG<3>::NCHK, KG<5>::NCHK, KG<7>::NCHK, KG<11>::NCHK,
                          KG<15>::NCHK, KG<23>::NCHK, KG<37>::NCHK, KG<55>::NCHK };
    PtrArgs a;
    int acc = 0;
    for (int i = 0; i < 8; ++i) {
        a.w[i]    = (const float*)d_in[1 + 2 * i];
        a.bias[i] = (const float*)d_in[2 + 2 * i];
        a.wpk[i]  = wpk0 + (size_t)acc * 2048;
        a.cum[i]  = acc;
        acc += nchk[i];
    }
    a.cum[8] = acc;   // 534 total chunks

    repack_all<<<acc, 256, 0, stream>>>(a);
    conv_all<<<dim3(256, 8), 256, 0, stream>>>(x, a, feat);
    gram_mfma<<<dim3(GCHK, 16), 256, 0, stream>>>(feat, perm, part);
    gram_reduce<<<dim3(65536 / 256), 256, 0, stream>>>(part, out);
}

// Round 7
// 136.513 us; speedup vs baseline: 1.5923x; 1.2525x over previous
//
#include <hip/hip_runtime.h>
#include <hip/hip_bf16.h>
#include <cstdint>

typedef __attribute__((ext_vector_type(8))) short short8;
typedef __attribute__((ext_vector_type(4))) short short4v;
typedef __attribute__((ext_vector_type(4))) float f32x4;

static constexpr int HWPIX = 16384;   // 128*128
static constexpr int NCH   = 512;
static constexpr int GCHK  = 32;      // gram pixel chunks (512 px each)

__device__ __forceinline__ unsigned short f2bf(float f) {
    unsigned int u = __float_as_uint(f);
    u = (u + 0x7fffu + ((u >> 16) & 1u)) >> 16;
    return (unsigned short)u;
}

// Conv: 64co x 128px (one image row) per block; kh processed in sections of 8
// input rows so LDS stays at 24*COLS bf16 (~8.7KB max) -> high occupancy.
// K-dim order per section: kw outer, icr = ic*8 + rr inner (rr = kh - 8*sec),
// SROW = 24 elems (SPC = 3, odd -> even bank coverage for strided b128 reads).
template<int K> struct KG {
    static constexpr int P    = (K - 1) / 2;
    static constexpr int NSEC = (K + 7) / 8;         // kh sections
    static constexpr int SROW = 24;                  // 3 ic * 8 rows
    static constexpr int SEGS = 3 * K;               // octet-segments per section
    static constexpr int NCHK = (SEGS + 3) / 4;      // MFMA K-32 chunks per section
    static constexpr int COLS = 128 + K - 1;
    static constexpr int XSE  = COLS * SROW;
};
static_assert(KG<55>::XSE * 2 < 9000, "lds small");

struct PtrArgs {
    const float* w[8];
    const float* bias[8];
    unsigned short* wpk[8];
    int cum[9];            // cumulative NSEC*NCHK per filter
};

// ---------------- weight repack ----------------
// layout per filter: [sec][chunk][costrip s][lane][8]; element for
// co = s*16+ln15, seg = chunk*4+lg -> kw = seg/3, r = seg%3; j -> icr=r*8+j,
// ic = icr>>3, kh = sec*8 + (icr&7).
template<int K>
__device__ void repack_body(const float* __restrict__ w, unsigned short* __restrict__ wpk, int t) {
    constexpr int NCHK = KG<K>::NCHK;
    const int sec = t / NCHK;
    const int tc  = t - sec * NCHK;
    const int tid = threadIdx.x;
    const int co  = ((tid >> 6) << 4) + (tid & 15);
    const int seg = tc * 4 + ((tid >> 4) & 3);
    int kw = 0, r = 0;
    const bool vseg = seg < KG<K>::SEGS;
    if (vseg) { kw = seg / 3; r = seg - kw * 3; }
    short8 o;
    #pragma unroll
    for (int j = 0; j < 8; ++j) {
        const int icr = r * 8 + j;
        const int ic  = icr >> 3;
        const int kh  = sec * 8 + (icr & 7);
        float v = 0.f;
        if (vseg && kh < K)
            v = w[((co * 3 + ic) * K + kh) * K + kw];
        o[j] = (short)f2bf(v);
    }
    *reinterpret_cast<short8*>(wpk + ((size_t)(t * 256 + tid)) * 8) = o;
}

__global__ __launch_bounds__(256) void repack_all(PtrArgs a) {
    const int blk = blockIdx.x;
    int f = 0;
    #pragma unroll
    for (int i = 0; i < 8; ++i) if (blk >= a.cum[i + 1]) f = i + 1;
    const int t = blk - a.cum[f];
    switch (f) {
        case 0: repack_body< 3>(a.w[0], a.wpk[0], t); break;
        case 1: repack_body< 5>(a.w[1], a.wpk[1], t); break;
        case 2: repack_body< 7>(a.w[2], a.wpk[2], t); break;
        case 3: repack_body<11>(a.w[3], a.wpk[3], t); break;
        case 4: repack_body<15>(a.w[4], a.wpk[4], t); break;
        case 5: repack_body<23>(a.w[5], a.wpk[5], t); break;
        case 6: repack_body<37>(a.w[6], a.wpk[6], t); break;
        case 7: repack_body<55>(a.w[7], a.wpk[7], t); break;
    }
}

// ---------------- conv: 256 thr, 4 waves; wave = 64co x 32px ----------------
#define MFMA_BF16 __builtin_amdgcn_mfma_f32_16x16x32_bf16

template<int K>
__device__ void conv_body(const float* __restrict__ x, const unsigned short* __restrict__ wpk,
                          const float* __restrict__ bias, unsigned short* __restrict__ feat,
                          int cbase, unsigned short* xs, int bx)
{
    constexpr int P    = KG<K>::P;
    constexpr int SEGS = KG<K>::SEGS;
    constexpr int NCHK = KG<K>::NCHK;
    constexpr int NSEC = KG<K>::NSEC;
    constexpr int COLS = KG<K>::COLS;

    const int tid = threadIdx.x;
    const int b   = bx >> 7;            // batch
    const int h   = bx & 127;           // image row

    const int lane = tid & 63;
    const int wv   = tid >> 6;          // 0..3 -> 32-px strip
    const int ln15 = lane & 15;
    const int lg   = lane >> 4;         // k-octet 0..3
    const int wvpx = wv * 32;

    f32x4 acc[4][2] = {};
    const float* xb = x + (size_t)b * 3 * HWPIX;
    const unsigned short* wl = wpk + (size_t)lane * 8;

    for (int s = 0; s < NSEC; ++s) {
        // stage 8 input rows (3 ic): xs[c][ic*8+rr] = x[ic][h + 8s + rr - P][c - P]
        if (s > 0) __syncthreads();     // all waves done reading previous section
        for (int e = tid * 4; e < 24 * COLS; e += 1024) {
            const int c  = e / 24;
            const int i0 = e - c * 24;
            const int col = c - P;
            short4v pk;
            #pragma unroll
            for (int j = 0; j < 4; ++j) {
                const int icr = i0 + j;
                const int ic  = icr >> 3;
                const int row = h + s * 8 + (icr & 7) - P;
                float v = 0.f;
                if ((unsigned)row < 128u && (unsigned)col < 128u)
                    v = xb[ic * HWPIX + row * 128 + col];
                pk[j] = (short)f2bf(v);
            }
            *reinterpret_cast<short4v*>(xs + e) = pk;
        }
        __syncthreads();

        const unsigned short* ws = wl + (size_t)s * NCHK * 2048;
        short8 a0 = *reinterpret_cast<const short8*>(ws + 0);
        short8 a1 = *reinterpret_cast<const short8*>(ws + 512);
        short8 a2 = *reinterpret_cast<const short8*>(ws + 1024);
        short8 a3 = *reinterpret_cast<const short8*>(ws + 1536);

        for (int t = 0; t < NCHK; ++t) {
            const int tn = (t + 1 < NCHK) ? t + 1 : t;
            const unsigned short* wn = ws + (size_t)tn * 2048;
            short8 n0 = *reinterpret_cast<const short8*>(wn + 0);
            short8 n1 = *reinterpret_cast<const short8*>(wn + 512);
            short8 n2 = *reinterpret_cast<const short8*>(wn + 1024);
            short8 n3 = *reinterpret_cast<const short8*>(wn + 1536);

            const int seg = t * 4 + lg;
            int kw = 0, r = 0;
            if (seg < SEGS) { kw = seg / 3; r = seg - kw * 3; }   // tail: zero wgts
            const unsigned short* bp = xs + (wvpx + ln15 + kw) * 24 + r * 8;
            short8 b0 = *reinterpret_cast<const short8*>(bp);
            short8 b1 = *reinterpret_cast<const short8*>(bp + 16 * 24);

            acc[0][0] = MFMA_BF16(a0, b0, acc[0][0], 0, 0, 0);
            acc[0][1] = MFMA_BF16(a0, b1, acc[0][1], 0, 0, 0);
            acc[1][0] = MFMA_BF16(a1, b0, acc[1][0], 0, 0, 0);
            acc[1][1] = MFMA_BF16(a1, b1, acc[1][1], 0, 0, 0);
            acc[2][0] = MFMA_BF16(a2, b0, acc[2][0], 0, 0, 0);
            acc[2][1] = MFMA_BF16(a2, b1, acc[2][1], 0, 0, 0);
            acc[3][0] = MFMA_BF16(a3, b0, acc[3][0], 0, 0, 0);
            acc[3][1] = MFMA_BF16(a3, b1, acc[3][1], 0, 0, 0);

            a0 = n0; a1 = n1; a2 = n2; a3 = n3;
        }
    }

    const int orow = h * 128;
    #pragma unroll
    for (int s = 0; s < 4; ++s)
        #pragma unroll
        for (int q = 0; q < 2; ++q)
            #pragma unroll
            for (int i = 0; i < 4; ++i) {
                const int co = s * 16 + lg * 4 + i;
                const int px = wvpx + q * 16 + ln15;
                float vv = fmaxf(acc[s][q][i] + bias[co], 0.f);
                feat[((size_t)(b * NCH + cbase + co)) * HWPIX + orow + px] = f2bf(vv);
            }
}

__global__ __launch_bounds__(256) void conv_all(const float* __restrict__ x,
                                                PtrArgs a, unsigned short* __restrict__ feat)
{
    __shared__ __align__(16) unsigned short xs[KG<55>::XSE];
    // LPT dispatch: heaviest filter (K=55) first so it spreads over all CUs
    switch (7 - blockIdx.y) {
        case 0: conv_body< 3>(x, a.wpk[0], a.bias[0], feat, 0 * 64, xs, blockIdx.x); break;
        case 1: conv_body< 5>(x, a.wpk[1], a.bias[1], feat, 1 * 64, xs, blockIdx.x); break;
        case 2: conv_body< 7>(x, a.wpk[2], a.bias[2], feat, 2 * 64, xs, blockIdx.x); break;
        case 3: conv_body<11>(x, a.wpk[3], a.bias[3], feat, 3 * 64, xs, blockIdx.x); break;
        case 4: conv_body<15>(x, a.wpk[4], a.bias[4], feat, 4 * 64, xs, blockIdx.x); break;
        case 5: conv_body<23>(x, a.wpk[5], a.bias[5], feat, 5 * 64, xs, blockIdx.x); break;
        case 6: conv_body<37>(x, a.wpk[6], a.bias[6], feat, 6 * 64, xs, blockIdx.x); break;
        case 7: conv_body<55>(x, a.wpk[7], a.bias[7], feat, 7 * 64, xs, blockIdx.x); break;
    }
}

// ---------------- gram via MFMA (unchanged, passing since r4) ----------------
__global__ __launch_bounds__(256) void gram_mfma(
    const unsigned short* __restrict__ feat, const int* __restrict__ perm,
    float* __restrict__ part)
{
    __shared__ __align__(16) unsigned short tile[64 * 256];
    __shared__ int permch[64];

    const int bg = blockIdx.y, chunk = blockIdx.x;
    const int b = bg >> 3, gq = bg & 7;
    const int tid = threadIdx.x;

    if (tid < 64) permch[tid] = perm[gq * 64 + tid];
    __syncthreads();

    const int lane = tid & 63;
    const int wv   = tid >> 6;
    const int ln15 = lane & 15;
    const int kg   = lane >> 4;

    f32x4 acc[4] = {};
    const size_t pxbase = (size_t)chunk * 512;

    for (int p2 = 0; p2 < 2; ++p2) {
        {
            const int r0 = tid >> 5;        // 0..7
            const int g  = tid & 31;        // 16B group 0..31
            #pragma unroll
            for (int it = 0; it < 8; ++it) {
                const int r = it * 8 + r0;
                const unsigned short* src =
                    feat + (((size_t)(b * NCH + permch[r])) << 14) + pxbase + p2 * 256 + g * 8;
                short8 v = *reinterpret_cast<const short8*>(src);
                *reinterpret_cast<short8*>(tile + r * 256 + ((g ^ (r & 7)) * 8)) = v;
            }
        }
        __syncthreads();
        #pragma unroll
        for (int t = 0; t < 8; ++t) {
            const int g  = t * 4 + kg;
            const int ra = wv * 16 + ln15;
            short8 av = *reinterpret_cast<const short8*>(tile + ra * 256 + ((g ^ (ra & 7)) * 8));
            #pragma unroll
            for (int cs = 0; cs < 4; ++cs) {
                const int rb = cs * 16 + ln15;
                short8 bv = *reinterpret_cast<const short8*>(tile + rb * 256 + ((g ^ (rb & 7)) * 8));
                acc[cs] = MFMA_BF16(av, bv, acc[cs], 0, 0, 0);
            }
        }
        __syncthreads();
    }

    float* pp = part + ((size_t)bg * GCHK + chunk) * 4096;
    #pragma unroll
    for (int cs = 0; cs < 4; ++cs)
        #pragma unroll
        for (int i = 0; i < 4; ++i) {
            const int row = wv * 16 + kg * 4 + i;
            const int col = cs * 16 + ln15;
            pp[row * 64 + col] = acc[cs][i];
        }
}

__global__ __launch_bounds__(256) void gram_reduce(
    const float* __restrict__ part, float* __restrict__ out)
{
    const int idx = blockIdx.x * 256 + threadIdx.x;   // 0..65535
    const int bg  = idx >> 12;
    const int e   = idx & 4095;
    const float* p = part + (size_t)bg * GCHK * 4096 + e;
    float s = 0.f;
    #pragma unroll
    for (int c = 0; c < GCHK; ++c) s += p[c * 4096];
    out[idx] = s;
}

extern "C" void kernel_launch(void* const* d_in, const int* in_sizes, int n_in,
                              void* d_out, int out_size, void* d_ws, size_t ws_size,
                              hipStream_t stream) {
    const float* x = (const float*)d_in[0];
    const int* perm = (const int*)d_in[17];

    // ws: feat bf16 32MiB | part 8MiB | wpk ~2.2MiB
    unsigned short* feat = (unsigned short*)d_ws;
    float* part = (float*)((char*)d_ws + (size_t)2 * NCH * HWPIX * sizeof(unsigned short));
    unsigned short* wpk0 = (unsigned short*)((char*)part + (size_t)16 * GCHK * 4096 * sizeof(float));
    float* out = (float*)d_out;

    const int nchk[8] = { KG<3>::NSEC * KG<3>::NCHK,  KG<5>::NSEC * KG<5>::NCHK,
                          KG<7>::NSEC * KG<7>::NCHK,  KG<11>::NSEC * KG<11>::NCHK,
                          KG<15>::NSEC * KG<15>::NCHK, KG<23>::NSEC * KG<23>::NCHK,
                          KG<37>::NSEC * KG<37>::NCHK, KG<55>::NSEC * KG<55>::NCHK };
    PtrArgs a;
    int acc = 0;
    for (int i = 0; i < 8; ++i) {
        a.w[i]    = (const float*)d_in[1 + 2 * i];
        a.bias[i] = (const float*)d_in[2 + 2 * i];
        a.wpk[i]  = wpk0 + (size_t)acc * 2048;
        a.cum[i]  = acc;
        acc += nchk[i];
    }
    a.cum[8] = acc;   // 543 total chunk-sections

    repack_all<<<acc, 256, 0, stream>>>(a);
    conv_all<<<dim3(256, 8), 256, 0, stream>>>(x, a, feat);
    gram_mfma<<<dim3(GCHK, 16), 256, 0, stream>>>(feat, perm, part);
    gram_reduce<<<dim3(65536 / 256), 256, 0, stream>>>(part, out);
}